// Round 20
// baseline (225.051 us; speedup 1.0000x reference)
//
#include <hip/hip_runtime.h>
#include <hip/hip_bf16.h>
#include <stdint.h>

#define NTOK 392
#define DIM  128
#define NH   4
#define HD   32
#define NCH  13
#define KST  36    // K_lds stride (shorts): 18 dwords, measured conflict-free
#define VST  396   // Vt stride (shorts): 198 dwords (=6 mod 32, same family)
#define L2E  1.44269504f
#define BPQ  416   // bias_perm shorts per q-row (13*32)

typedef __attribute__((ext_vector_type(4))) float f32x4;
typedef __attribute__((ext_vector_type(4))) short s16x4;
typedef __attribute__((ext_vector_type(8))) short s16x8;

union Frag { s16x8 v; struct { s16x4 lo, hi; } h; };
union PF { s16x8 v; uint32_t u[4]; };

__device__ __forceinline__ short f2bf(float f) {
  union { float f; uint32_t u; } v; v.f = f;
  uint32_t r = v.u + 0x7fffu + ((v.u >> 16) & 1u);
  return (short)(r >> 16);
}
// RNE pack via HW (bit-identical to f2bf); 2 insts per 4 values
__device__ __forceinline__ s16x4 cvt4(f32x4 a) {
  union { s16x4 s; uint32_t u[2]; } r;
  asm("v_cvt_pk_bf16_f32 %0, %1, %2" : "=v"(r.u[0]) : "v"(a.x), "v"(a.y));
  asm("v_cvt_pk_bf16_f32 %0, %1, %2" : "=v"(r.u[1]) : "v"(a.z), "v"(a.w));
  return r.s;
}
// raw v_exp_f32 (args bounded: <= ~12 by defer-max; denorm flush OK)
__device__ __forceinline__ float fexp2(float x) {
  float r; asm("v_exp_f32 %0, %1" : "=v"(r) : "v"(x)); return r;
}
// bf16x8 -> 2x f32x4 (2 VALU per dword: shl16 / and-hi)
__device__ __forceinline__ void bb2f(s16x8 b, f32x4& lo, f32x4& hi) {
  union { s16x8 s; uint32_t u[4]; } x; x.s = b;
  union { uint32_t u; float f; } t;
  t.u = x.u[0] << 16;          lo.x = t.f;
  t.u = x.u[0] & 0xffff0000u;  lo.y = t.f;
  t.u = x.u[1] << 16;          lo.z = t.f;
  t.u = x.u[1] & 0xffff0000u;  lo.w = t.f;
  t.u = x.u[2] << 16;          hi.x = t.f;
  t.u = x.u[2] & 0xffff0000u;  hi.y = t.f;
  t.u = x.u[3] << 16;          hi.z = t.f;
  t.u = x.u[3] & 0xffff0000u;  hi.w = t.f;
}

// online-softmax + PV step; s0/s1 already include mask+bias (via MFMA C-init)
// (r12-verified body: fexp2 + defer-max + cvt_pk)
__device__ __forceinline__ void sm_pv(f32x4 s0, f32x4 s1,
                                      f32x4& o0, f32x4& o1,
                                      float& mrun, float& nmrl, float& lrun,
                                      const Frag& vf0, const Frag& vf1) {
  float cm = fmaxf(fmaxf(fmaxf(s0.x, s0.y), fmaxf(s0.z, s0.w)),
                   fmaxf(fmaxf(s1.x, s1.y), fmaxf(s1.z, s1.w)));
  if (__any(cm > mrun + 8.f)) {         // rare: true running-max rescale
    float tmx = fmaxf(cm, __shfl_xor(cm, 16));
    tmx = fmaxf(tmx, __shfl_xor(tmx, 32));
    const float mnew = fmaxf(mrun, tmx);
    const float al = fexp2((mrun - mnew) * L2E);
    #pragma unroll
    for (int rr = 0; rr < 4; ++rr) { o0[rr] *= al; o1[rr] *= al; }
    lrun *= al; mrun = mnew; nmrl = -mnew * L2E;
  }
  float p0 = fexp2(fmaf(s0.x, L2E, nmrl));
  float p1 = fexp2(fmaf(s0.y, L2E, nmrl));
  float p2 = fexp2(fmaf(s0.z, L2E, nmrl));
  float p3 = fexp2(fmaf(s0.w, L2E, nmrl));
  float p4 = fexp2(fmaf(s1.x, L2E, nmrl));
  float p5 = fexp2(fmaf(s1.y, L2E, nmrl));
  float p6 = fexp2(fmaf(s1.z, L2E, nmrl));
  float p7 = fexp2(fmaf(s1.w, L2E, nmrl));
  lrun += ((p0 + p1) + (p2 + p3)) + ((p4 + p5) + (p6 + p7));
  PF pf;
  asm("v_cvt_pk_bf16_f32 %0, %1, %2" : "=v"(pf.u[0]) : "v"(p0), "v"(p1));
  asm("v_cvt_pk_bf16_f32 %0, %1, %2" : "=v"(pf.u[1]) : "v"(p2), "v"(p3));
  asm("v_cvt_pk_bf16_f32 %0, %1, %2" : "=v"(pf.u[2]) : "v"(p4), "v"(p5));
  asm("v_cvt_pk_bf16_f32 %0, %1, %2" : "=v"(pf.u[3]) : "v"(p6), "v"(p7));
  o0 = __builtin_amdgcn_mfma_f32_16x16x32_bf16(vf0.v, pf.v, o0, 0, 0, 0);
  o1 = __builtin_amdgcn_mfma_f32_16x16x32_bf16(vf1.v, pf.v, o1, 0, 0, 0);
}

// ---- K0: fused prep — bias -> frag-ordered bf16 (pad poisoned) + weights
// ---- -> bf16 (one-time) ----------------------------------------------------
__global__ void k_prep(const float* __restrict__ bt, const int* __restrict__ ri,
                       short* __restrict__ bias_perm,
                       const float* __restrict__ qkvw, const float* __restrict__ pw,
                       short* __restrict__ wq_bf, short* __restrict__ wp_bf) {
  int i = blockIdx.x * 256 + threadIdx.x;
  if (i < 3 * DIM * DIM) wq_bf[i] = f2bf(qkvw[i]);
  if (i < DIM * DIM)     wp_bf[i] = f2bf(pw[i]);
  if (i >= NH * NTOK * BPQ) return;
  int h = i / (NTOK * BPQ);
  int r = i - h * (NTOK * BPQ);
  int q = r / BPQ;
  int p = r - q * BPQ;               // c*32 + g*8 + hb*4 + j
  int c = p >> 5, w2 = p & 31;
  int g = w2 >> 3, hb = (w2 >> 2) & 1, jj = w2 & 3;
  int kv = c * 32 + hb * 16 + g * 4 + jj;
  float v = -3e30f;
  if (kv < NTOK) v = bt[ri[q * NTOK + kv] * NH + h];
  bias_perm[i] = f2bf(v);
}

// ------- K1: qkv = x @ qkv_w^T, bf16 out, q pre-scaled; fused z-loop ---------
__global__ __launch_bounds__(256, 3)
void k_qkv(const float* __restrict__ x, const short* __restrict__ wq_bf,
           short* __restrict__ q_ws, short* __restrict__ k_ws,
           short* __restrict__ v_ws) {
  __shared__ short xs[64 * 136];
  __shared__ short wl[128 * 136];
  const int t  = threadIdx.x;
  const int m0 = blockIdx.x * 64;
  {
    const int r = t >> 2, c0 = (t & 3) * 32;
    const float* src = x + (size_t)(m0 + r) * DIM + c0;
    short* dst = xs + r * 136 + c0;
    #pragma unroll
    for (int i = 0; i < 8; ++i)
      *(s16x4*)(dst + 4*i) = cvt4(*(const f32x4*)(src + 4*i));
  }
  const int l = t & 63, w = t >> 6, lr = l & 15, g = l >> 4;
  const int m = m0 + w * 16 + lr;
  const int b = m / NTOK;
  const int n = m - b * NTOK;
  #pragma unroll 1
  for (int z = 0; z < 3; ++z) {
    {
      const int r = t >> 1, c0 = (t & 1) * 64;
      const short* src = wq_bf + (size_t)(z * DIM + r) * DIM + c0;
      short* dst = wl + r * 136 + c0;
      #pragma unroll
      for (int i = 0; i < 8; ++i)
        *(s16x8*)(dst + 8*i) = *(const s16x8*)(src + 8*i);
    }
    __syncthreads();
    f32x4 acc[8] = {};
    #pragma unroll
    for (int ks = 0; ks < 4; ++ks) {
      const int k0 = ks * 32 + 4 * g;
      Frag xb;
      const short* bp = xs + (w * 16 + lr) * 136 + k0;
      xb.h.lo = *(const s16x4*)bp; xb.h.hi = *(const s16x4*)(bp + 16);
      #pragma unroll
      for (int ct = 0; ct < 8; ++ct) {
        const short* ap = wl + (ct * 16 + lr) * 136 + k0;
        Frag wa; wa.h.lo = *(const s16x4*)ap; wa.h.hi = *(const s16x4*)(ap + 16);
        acc[ct] = __builtin_amdgcn_mfma_f32_16x16x32_bf16(wa.v, xb.v, acc[ct], 0, 0, 0);
      }
    }
    short* outp = (z == 0) ? q_ws : (z == 1 ? k_ws : v_ws);
    const float scale = (z == 0) ? 0.17677669529663689f : 1.0f;
    #pragma unroll
    for (int ct = 0; ct < 8; ++ct) {
      const int c0 = ct * 16 + 4 * g;       // 4 consecutive channels
      const int hh = c0 >> 5, d = c0 & 31;
      f32x4 sc = acc[ct];
      sc.x *= scale; sc.y *= scale; sc.z *= scale; sc.w *= scale;
      *(s16x4*)(outp + (((size_t)b * NH + hh) * NTOK + n) * HD + d) = cvt4(sc);
    }
    __syncthreads();
  }
}

// ---- K2: per-(window,head) attention, KVBLK=32, TWO q-tile streams/wave ----
// ---- (r5 mapping, verified) sharing K/V frags; per-stream raw distance-1 ---
// ---- mask/bias slots (r6, verified); (512,2) -> VGPR cap 128 so both -------
// ---- streams' slots stay live (r5's null was the VGPR-64 straitjacket). ----
__global__ __launch_bounds__(512, 2)
void k_attn(const short* __restrict__ q_ws, const short* __restrict__ k_ws,
            const short* __restrict__ v_ws, const float* __restrict__ mask,
            const short* __restrict__ bias_perm, short* __restrict__ y_ws) {
  __shared__ short K_l[NTOK * KST];   // [392][36] shorts = 28224 B
  __shared__ short Vt[HD * VST];      // [32][396] shorts = 25344 B
  const int t = threadIdx.x;
  // XCD swizzle: 4 heads of one window land on the same XCD, adjacent slots
  const int j = blockIdx.x, xcd = j & 7, slot = j >> 3;
  const int b = (xcd << 5) | (slot >> 2);
  const int h = slot & 3;
  const size_t bh = (size_t)b * NH + h;
  const short* kp = k_ws + bh * NTOK * HD;
  const short* vp = v_ws + bh * NTOK * HD;
  const short* qp = q_ws + bh * NTOK * HD;
  const float* mp = mask + (size_t)b * NTOK * NTOK;
  const short* bph = bias_perm + (size_t)h * NTOK * BPQ;
  // stage K (real rows only; tail reads are clamped)
  for (int r = t; r < NTOK; r += 512) {
    short* dst = K_l + r * KST;
    const s16x4* src = (const s16x4*)(kp + r * HD);
    #pragma unroll
    for (int i = 0; i < 8; ++i) *(s16x4*)(dst + 4*i) = src[i];
  }
  // stage V transposed (real cols only; tail reads are clamped)
  for (int n = t; n < NTOK; n += 512) {
    union { s16x4 v4[8]; short s[32]; } vv;
    const s16x4* src = (const s16x4*)(vp + n * HD);
    #pragma unroll
    for (int i = 0; i < 8; ++i) vv.v4[i] = src[i];
    #pragma unroll
    for (int d = 0; d < 32; ++d) Vt[d * VST + n] = vv.s[d];
  }
  __syncthreads();
  const int l = t & 63, w = t >> 6, lr = l & 15, g = l >> 4;
  const int og0 = 4 * g, og1 = 16 + 4 * g;
  #pragma unroll 1
  for (int pass = 0; pass < 2; ++pass) {
    const int T0 = w + pass * 16, T1 = T0 + 8;     // two tiles per wave
    const bool do1 = (T1 < 25);                    // wave-uniform
    const int qrowA = T0 * 16 + lr;                // always < NTOK (T0<=23)
    const int qrowB = T1 * 16 + lr;
    const int qcB = qrowB < NTOK ? qrowB : NTOK - 1;
    Frag qfA, qfB;
    { const short* qa = qp + qrowA * HD + 4 * g;
      qfA.h.lo = *(const s16x4*)qa; qfA.h.hi = *(const s16x4*)(qa + 16); }
    { const short* qa = qp + qcB * HD + 4 * g;
      qfB.h.lo = *(const s16x4*)qa; qfB.h.hi = *(const s16x4*)(qa + 16); }
    const float* mrowA = mp + (size_t)qrowA * NTOK;
    const short* browA = bph + qrowA * BPQ;
    const float* mrowB = mp + (size_t)qcB * NTOK;
    const short* browB = bph + qcB * BPQ;
    // per-stream raw 2-slot rings (distance-1)
    f32x4 maf0[2], maf1[2], mbf0[2], mbf1[2];
    s16x8 baf[2], bbf[2];
    maf0[0] = *(const f32x4*)(mrowA + og0);
    maf1[0] = *(const f32x4*)(mrowA + og1);
    baf[0]  = *(const s16x8*)(browA + g * 8);
    if (do1) {
      mbf0[0] = *(const f32x4*)(mrowB + og0);
      mbf1[0] = *(const f32x4*)(mrowB + og1);
      bbf[0]  = *(const s16x8*)(browB + g * 8);
    }
    f32x4 oA0 = {0,0,0,0}, oA1 = {0,0,0,0}, oB0 = {0,0,0,0}, oB1 = {0,0,0,0};
    float mrunA = 0.f, nmrlA = 0.f, lrunA = 0.f;
    float mrunB = 0.f, nmrlB = 0.f, lrunB = 0.f;
    #pragma unroll
    for (int c = 0; c < NCH; ++c) {
      const int sl = c & 1, nx = sl ^ 1;  // static after unroll
      if (c < NCH - 1) {                   // distance-1 prefetch of c+1
        const int cc = c + 1;
        if (cc < NCH - 1) {
          const int base = cc * 32;
          maf0[nx] = *(const f32x4*)(mrowA + base + og0);
          maf1[nx] = *(const f32x4*)(mrowA + base + og1);
          baf[nx]  = *(const s16x8*)(browA + base + g * 8);
          if (do1) {
            mbf0[nx] = *(const f32x4*)(mrowB + base + og0);
            mbf1[nx] = *(const f32x4*)(mrowB + base + og1);
            bbf[nx]  = *(const s16x8*)(browB + base + g * 8);
          }
        } else {                           // tail chunk 12: bias poison covers pads
          int a0 = 384 + og0; if (a0 > 388) a0 = 388;
          maf0[nx] = *(const f32x4*)(mrowA + a0);
          maf1[nx] = *(const f32x4*)(mrowA + 388);
          baf[nx]  = *(const s16x8*)(browA + 384 + g * 8);
          if (do1) {
            mbf0[nx] = *(const f32x4*)(mrowB + a0);
            mbf1[nx] = *(const f32x4*)(mrowB + 388);
            bbf[nx]  = *(const s16x8*)(browB + 384 + g * 8);
          }
        }
      }
      const int kv0 = c * 32;
      // row/col bases; tail chunk clamps into the real region (compile-time
      // branch under full unroll). Clamped lanes' outputs are p=0 slots.
      int r0 = kv0 + lr, r1 = kv0 + 16 + lr;
      int cb0 = kv0 + 4 * g, cb1 = kv0 + 16 + 4 * g;
      if (c == NCH - 1) {
        r0 = r0 < NTOK ? r0 : NTOK - 1;
        r1 = NTOK - 1;
        cb0 = cb0 < 388 ? cb0 : 388;
        cb1 = 388;
      }
      // shared K/V frags
      Frag ka0, ka1, vf0, vf1;
      { const short* p0 = K_l + r0 * KST + 4 * g;
        ka0.h.lo = *(const s16x4*)p0; ka0.h.hi = *(const s16x4*)(p0 + 16);
        const short* p1 = K_l + r1 * KST + 4 * g;
        ka1.h.lo = *(const s16x4*)p1; ka1.h.hi = *(const s16x4*)(p1 + 16);
        const short* v0 = Vt + lr * VST;
        vf0.h.lo = *(const s16x4*)(v0 + cb0); vf0.h.hi = *(const s16x4*)(v0 + cb1);
        const short* v1 = Vt + (16 + lr) * VST;
        vf1.h.lo = *(const s16x4*)(v1 + cb0); vf1.h.hi = *(const s16x4*)(v1 + cb1); }
      __builtin_amdgcn_s_setprio(1);      // T5: favor this wave thru compute
      // stream A (C-init = mask + bias, from 1-chunk-old regs)
      { f32x4 aL, aH;
        bb2f(baf[sl], aL, aH);
        f32x4 c0 = maf0[sl] + aL;
        f32x4 c1 = maf1[sl] + aH;
        f32x4 s0 = __builtin_amdgcn_mfma_f32_16x16x32_bf16(ka0.v, qfA.v, c0, 0,0,0);
        f32x4 s1 = __builtin_amdgcn_mfma_f32_16x16x32_bf16(ka1.v, qfA.v, c1, 0,0,0);
        sm_pv(s0, s1, oA0, oA1, mrunA, nmrlA, lrunA, vf0, vf1);
      }
      // stream B
      if (do1) {
        f32x4 bL, bH;
        bb2f(bbf[sl], bL, bH);
        f32x4 c0 = mbf0[sl] + bL;
        f32x4 c1 = mbf1[sl] + bH;
        f32x4 s0 = __builtin_amdgcn_mfma_f32_16x16x32_bf16(ka0.v, qfB.v, c0, 0,0,0);
        f32x4 s1 = __builtin_amdgcn_mfma_f32_16x16x32_bf16(ka1.v, qfB.v, c1, 0,0,0);
        sm_pv(s0, s1, oB0, oB1, mrunB, nmrlB, lrunB, vf0, vf1);
      }
      __builtin_amdgcn_s_setprio(0);
    }
    // stream A write-out (qrowA always valid)
    {
      float lt = lrunA + __shfl_xor(lrunA, 16);
      lt += __shfl_xor(lt, 32);
      const float inv = 1.0f / lt;
      short* yb = y_ws + ((size_t)b * NTOK + qrowA) * DIM + h * HD;
      s16x4 r0v, r1v;
      #pragma unroll
      for (int rr = 0; rr < 4; ++rr) { r0v[rr] = f2bf(oA0[rr] * inv); r1v[rr] = f2bf(oA1[rr] * inv); }
      *(s16x4*)(yb + 4 * g) = r0v;
      *(s16x4*)(yb + 16 + 4 * g) = r1v;
    }
    if (do1) {
      float lt = lrunB + __shfl_xor(lrunB, 16);
      lt += __shfl_xor(lt, 32);
      if (qrowB < NTOK) {
        const float inv = 1.0f / lt;
        short* yb = y_ws + ((size_t)b * NTOK + qrowB) * DIM + h * HD;
        s16x4 r0v, r1v;
        #pragma unroll
        for (int rr = 0; rr < 4; ++rr) { r0v[rr] = f2bf(oB0[rr] * inv); r1v[rr] = f2bf(oB1[rr] * inv); }
        *(s16x4*)(yb + 4 * g) = r0v;
        *(s16x4*)(yb + 16 + 4 * g) = r1v;
      }
    }
  }
}

// ---------------- K3: out = y @ proj_w^T + proj_b -----------------------------
__global__ __launch_bounds__(256, 3)
void k_proj(const short* __restrict__ y_ws, const short* __restrict__ wp_bf,
            const float* __restrict__ pb, float* __restrict__ out) {
  __shared__ short ys[64 * 136];
  __shared__ short wl[128 * 136];
  const int t = threadIdx.x;
  const int m0 = blockIdx.x * 64;
  {
    const int r = t >> 2, c0 = (t & 3) * 32;
    const s16x4* src = (const s16x4*)(y_ws + (size_t)(m0 + r) * DIM + c0);
    short* dst = ys + r * 136 + c0;
    #pragma unroll
    for (int i = 0; i < 8; ++i) *(s16x4*)(dst + 4*i) = src[i];
  }
  {
    const int r = t >> 1, c0 = (t & 1) * 64;
    const short* src = wp_bf + (size_t)r * DIM + c0;
    short* dst = wl + r * 136 + c0;
    #pragma unroll
    for (int i = 0; i < 8; ++i)
      *(s16x8*)(dst + 8*i) = *(const s16x8*)(src + 8*i);
  }
  __syncthreads();
  const int l = t & 63, w = t >> 6, lr = l & 15, g = l >> 4;
  const int m = m0 + w * 16 + lr;
  f32x4 acc[8] = {};
  #pragma unroll
  for (int ks = 0; ks < 4; ++ks) {
    const int k0 = ks * 32 + 4 * g;
    Frag ya;
    const short* bp = ys + (w * 16 + lr) * 136 + k0;
    ya.h.lo = *(const s16x4*)bp; ya.h.hi = *(const s16x4*)(bp + 16);
    #pragma unroll
    for (int ct = 0; ct < 8; ++ct) {
      const short* ap = wl + (ct * 16 + lr) * 136 + k0;
      Frag wa; wa.h.lo = *(const s16x4*)ap; wa.h.hi = *(const s16x4*)(ap + 16);
      acc[ct] = __builtin_amdgcn_mfma_f32_16x16x32_bf16(wa.v, ya.v, acc[ct], 0, 0, 0);
    }
  }
  #pragma unroll
  for (int ct = 0; ct < 8; ++ct) {
    const int c0 = ct * 16 + 4 * g;
    const f32x4 pbv = *(const f32x4*)(pb + c0);
    f32x4 res = acc[ct] + pbv;
    *(f32x4*)(out + (size_t)m * DIM + c0) = res;
  }
}

extern "C" void kernel_launch(void* const* d_in, const int* in_sizes, int n_in,
                              void* d_out, int out_size, void* d_ws, size_t ws_size,
                              hipStream_t stream) {
  const float* x    = (const float*)d_in[0];
  const float* mask = (const float*)d_in[1];
  const float* bt   = (const float*)d_in[2];
  const int*   ri   = (const int*)d_in[3];
  const float* qkvw = (const float*)d_in[4];
  const float* pw   = (const float*)d_in[5];
  const float* pb   = (const float*)d_in[6];
  float* out = (float*)d_out;
  // ws layout: 4 x 25.69MB bf16 tensors + 1.3MB bias_perm + 128KB bf16 weights
  const size_t TEN = (size_t)256 * NH * NTOK * HD;   // 12,845,056
  short* q_ws = (short*)d_ws;
  short* k_ws = q_ws + TEN;
  short* v_ws = k_ws + TEN;
  short* y_ws = v_ws + TEN;
  short* bias_perm = y_ws + TEN;                     // NH*NTOK*BPQ shorts
  short* wq_bf = bias_perm + (size_t)NH * NTOK * BPQ; // 3*128*128 shorts
  short* wp_bf = wq_bf + 3 * DIM * DIM;               // 128*128 shorts
  k_prep<<<(NH * NTOK * BPQ + 255) / 256, 256, 0, stream>>>(bt, ri, bias_perm,
                                                            qkvw, pw, wq_bf, wp_bf);
  k_qkv<<<1568, 256, 0, stream>>>(x, wq_bf, q_ws, k_ws, v_ws);
  k_attn<<<1024, 512, 0, stream>>>(q_ws, k_ws, v_ws, mask, bias_perm, y_ws);
  k_proj<<<1568, 256, 0, stream>>>(y_ws, wp_bf, pb, out);
}

// Round 21
// 191.411 us; speedup vs baseline: 1.1757x; 1.1757x over previous
//
#include <hip/hip_runtime.h>
#include <hip/hip_bf16.h>
#include <stdint.h>

#define NTOK 392
#define DIM  128
#define NH   4
#define HD   32
#define KST  36    // K_lds stride (shorts): 18 dwords, measured conflict-free
#define VST  396   // Vt stride (shorts): 198 dwords (=6 mod 32, same family)
#define L2E  1.44269504f
#define BPQ  416   // bias_perm shorts per q-row (13*32)

typedef __attribute__((ext_vector_type(4))) float f32x4;
typedef __attribute__((ext_vector_type(4))) short s16x4;
typedef __attribute__((ext_vector_type(8))) short s16x8;

union Frag { s16x8 v; struct { s16x4 lo, hi; } h; };
union PF { s16x8 v; uint32_t u[4]; };

__device__ __forceinline__ short f2bf(float f) {
  union { float f; uint32_t u; } v; v.f = f;
  uint32_t r = v.u + 0x7fffu + ((v.u >> 16) & 1u);
  return (short)(r >> 16);
}
// RNE pack via HW (bit-identical to f2bf); 2 insts per 4 values
__device__ __forceinline__ s16x4 cvt4(f32x4 a) {
  union { s16x4 s; uint32_t u[2]; } r;
  asm("v_cvt_pk_bf16_f32 %0, %1, %2" : "=v"(r.u[0]) : "v"(a.x), "v"(a.y));
  asm("v_cvt_pk_bf16_f32 %0, %1, %2" : "=v"(r.u[1]) : "v"(a.z), "v"(a.w));
  return r.s;
}
// raw v_exp_f32 (args bounded: <= ~12 by defer-max; denorm flush OK)
__device__ __forceinline__ float fexp2(float x) {
  float r; asm("v_exp_f32 %0, %1" : "=v"(r) : "v"(x)); return r;
}
// bf16x8 -> 2x f32x4 (2 VALU per dword: shl16 / and-hi)
__device__ __forceinline__ void bb2f(s16x8 b, f32x4& lo, f32x4& hi) {
  union { s16x8 s; uint32_t u[4]; } x; x.s = b;
  union { uint32_t u; float f; } t;
  t.u = x.u[0] << 16;          lo.x = t.f;
  t.u = x.u[0] & 0xffff0000u;  lo.y = t.f;
  t.u = x.u[1] << 16;          lo.z = t.f;
  t.u = x.u[1] & 0xffff0000u;  lo.w = t.f;
  t.u = x.u[2] << 16;          hi.x = t.f;
  t.u = x.u[2] & 0xffff0000u;  hi.y = t.f;
  t.u = x.u[3] << 16;          hi.z = t.f;
  t.u = x.u[3] & 0xffff0000u;  hi.w = t.f;
}

// ---- K0: fused prep — bias -> frag-ordered bf16 (pad poisoned) + weights
// ---- -> bf16 (one-time) ----------------------------------------------------
__global__ void k_prep(const float* __restrict__ bt, const int* __restrict__ ri,
                       short* __restrict__ bias_perm,
                       const float* __restrict__ qkvw, const float* __restrict__ pw,
                       short* __restrict__ wq_bf, short* __restrict__ wp_bf) {
  int i = blockIdx.x * 256 + threadIdx.x;
  if (i < 3 * DIM * DIM) wq_bf[i] = f2bf(qkvw[i]);
  if (i < DIM * DIM)     wp_bf[i] = f2bf(pw[i]);
  if (i >= NH * NTOK * BPQ) return;
  int h = i / (NTOK * BPQ);
  int r = i - h * (NTOK * BPQ);
  int q = r / BPQ;
  int p = r - q * BPQ;               // c*32 + g*8 + hb*4 + j
  int c = p >> 5, w2 = p & 31;
  int g = w2 >> 3, hb = (w2 >> 2) & 1, jj = w2 & 3;
  int kv = c * 32 + hb * 16 + g * 4 + jj;
  float v = -3e30f;
  if (kv < NTOK) v = bt[ri[q * NTOK + kv] * NH + h];
  bias_perm[i] = f2bf(v);
}

// ------- K1: qkv = x @ qkv_w^T, bf16 out, q pre-scaled; fused z-loop ---------
__global__ __launch_bounds__(256, 3)
void k_qkv(const float* __restrict__ x, const short* __restrict__ wq_bf,
           short* __restrict__ q_ws, short* __restrict__ k_ws,
           short* __restrict__ v_ws) {
  __shared__ short xs[64 * 136];
  __shared__ short wl[128 * 136];
  const int t  = threadIdx.x;
  const int m0 = blockIdx.x * 64;
  {
    const int r = t >> 2, c0 = (t & 3) * 32;
    const float* src = x + (size_t)(m0 + r) * DIM + c0;
    short* dst = xs + r * 136 + c0;
    #pragma unroll
    for (int i = 0; i < 8; ++i)
      *(s16x4*)(dst + 4*i) = cvt4(*(const f32x4*)(src + 4*i));
  }
  const int l = t & 63, w = t >> 6, lr = l & 15, g = l >> 4;
  const int m = m0 + w * 16 + lr;
  const int b = m / NTOK;
  const int n = m - b * NTOK;
  #pragma unroll 1
  for (int z = 0; z < 3; ++z) {
    {
      const int r = t >> 1, c0 = (t & 1) * 64;
      const short* src = wq_bf + (size_t)(z * DIM + r) * DIM + c0;
      short* dst = wl + r * 136 + c0;
      #pragma unroll
      for (int i = 0; i < 8; ++i)
        *(s16x8*)(dst + 8*i) = *(const s16x8*)(src + 8*i);
    }
    __syncthreads();
    f32x4 acc[8] = {};
    #pragma unroll
    for (int ks = 0; ks < 4; ++ks) {
      const int k0 = ks * 32 + 4 * g;
      Frag xb;
      const short* bp = xs + (w * 16 + lr) * 136 + k0;
      xb.h.lo = *(const s16x4*)bp; xb.h.hi = *(const s16x4*)(bp + 16);
      #pragma unroll
      for (int ct = 0; ct < 8; ++ct) {
        const short* ap = wl + (ct * 16 + lr) * 136 + k0;
        Frag wa; wa.h.lo = *(const s16x4*)ap; wa.h.hi = *(const s16x4*)(ap + 16);
        acc[ct] = __builtin_amdgcn_mfma_f32_16x16x32_bf16(wa.v, xb.v, acc[ct], 0, 0, 0);
      }
    }
    short* outp = (z == 0) ? q_ws : (z == 1 ? k_ws : v_ws);
    const float scale = (z == 0) ? 0.17677669529663689f : 1.0f;
    #pragma unroll
    for (int ct = 0; ct < 8; ++ct) {
      const int c0 = ct * 16 + 4 * g;       // 4 consecutive channels
      const int hh = c0 >> 5, d = c0 & 31;
      f32x4 sc = acc[ct];
      sc.x *= scale; sc.y *= scale; sc.z *= scale; sc.w *= scale;
      *(s16x4*)(outp + (((size_t)b * NH + hh) * NTOK + n) * HD + d) = cvt4(sc);
    }
    __syncthreads();
  }
}

// ---- K2: per-(window,head) attention. KVBLK=64, 7 chunks/tile. -------------
// ---- r18/r19-verified body. r21: 640 threads (10 waves) so the worst wave
// ---- carries 3 tile-chains instead of 4 (25 tiles / 10 waves); LDS still
// ---- fits 2 blocks/CU; (640,2) -> 20 waves/CU -> VGPR cap ~102 >= 88. ------
__global__ __launch_bounds__(640, 2)
void k_attn(const short* __restrict__ q_ws, const short* __restrict__ k_ws,
            const short* __restrict__ v_ws, const float* __restrict__ mask,
            const short* __restrict__ bias_perm, short* __restrict__ y_ws) {
  __shared__ short K_l[NTOK * KST];   // [392][36] shorts = 28224 B
  __shared__ short Vt[HD * VST];      // [32][396] shorts = 25344 B
  const int t = threadIdx.x;
  // XCD swizzle: 4 heads of one window land on the same XCD, adjacent slots
  const int j = blockIdx.x, xcd = j & 7, slot = j >> 3;
  const int b = (xcd << 5) | (slot >> 2);
  const int h = slot & 3;
  const size_t bh = (size_t)b * NH + h;
  const short* kp = k_ws + bh * NTOK * HD;
  const short* vp = v_ws + bh * NTOK * HD;
  const short* qp = q_ws + bh * NTOK * HD;
  const float* mp = mask + (size_t)b * NTOK * NTOK;
  const short* bph = bias_perm + (size_t)h * NTOK * BPQ;
  // stage K (real rows only; tail reads are clamped)
  for (int r = t; r < NTOK; r += 640) {
    short* dst = K_l + r * KST;
    const s16x4* src = (const s16x4*)(kp + r * HD);
    #pragma unroll
    for (int i = 0; i < 8; ++i) *(s16x4*)(dst + 4*i) = src[i];
  }
  // stage V transposed (real cols only; tail reads are clamped)
  for (int n = t; n < NTOK; n += 640) {
    union { s16x4 v4[8]; short s[32]; } vv;
    const s16x4* src = (const s16x4*)(vp + n * HD);
    #pragma unroll
    for (int i = 0; i < 8; ++i) vv.v4[i] = src[i];
    #pragma unroll
    for (int d = 0; d < 32; ++d) Vt[d * VST + n] = vv.s[d];
  }
  __syncthreads();
  const int l = t & 63, w = t >> 6, lr = l & 15, g = l >> 4;
  const int og0 = 4 * g, og1 = 16 + 4 * g;
  #pragma unroll 1
  for (int q0 = w * 16; q0 < NTOK; q0 += 160) {
    const int qrow = q0 + lr;
    const int qc = qrow < NTOK ? qrow : NTOK - 1;
    Frag qf;
    { const short* qa = qp + qc * HD + 4 * g;
      qf.h.lo = *(const s16x4*)qa; qf.h.hi = *(const s16x4*)(qa + 16); }
    const float* mrow = mp + (size_t)qc * NTOK;
    const short* brow = bph + qc * BPQ;
    // 2 fat slots (64 kv each), distance-1 prefetch, raw at issue
    f32x4 mA0[2], mA1[2], mB0[2], mB1[2];
    s16x8 bA[2], bB[2];
    mA0[0] = *(const f32x4*)(mrow + og0);
    mA1[0] = *(const f32x4*)(mrow + og1);
    mB0[0] = *(const f32x4*)(mrow + 32 + og0);
    mB1[0] = *(const f32x4*)(mrow + 32 + og1);
    bA[0]  = *(const s16x8*)(brow + g * 8);
    bB[0]  = *(const s16x8*)(brow + 32 + g * 8);
    f32x4 o0 = {0,0,0,0}, o1 = {0,0,0,0};
    float mrun = 0.f, nmrl = 0.f, lrun = 0.f;
    #pragma unroll
    for (int c = 0; c < 7; ++c) {
      const int sl = c & 1, nx = sl ^ 1;   // static after unroll
      if (c < 6) {                          // distance-1 prefetch of c+1
        const int base = (c + 1) * 64;
        if (c + 1 < 6) {
          mA0[nx] = *(const f32x4*)(mrow + base + og0);
          mA1[nx] = *(const f32x4*)(mrow + base + og1);
          mB0[nx] = *(const f32x4*)(mrow + base + 32 + og0);
          mB1[nx] = *(const f32x4*)(mrow + base + 32 + og1);
          bA[nx]  = *(const s16x8*)(brow + base + g * 8);
          bB[nx]  = *(const s16x8*)(brow + base + 32 + g * 8);
        } else {                            // tail: half A only (old chunk 12)
          int a0 = 384 + og0; if (a0 > 388) a0 = 388;
          mA0[nx] = *(const f32x4*)(mrow + a0);
          mA1[nx] = *(const f32x4*)(mrow + 388);
          bA[nx]  = *(const s16x8*)(brow + 384 + g * 8);
        }
      }
      const int kv0 = c * 64;
      int rA0 = kv0 + lr, rA1 = kv0 + 16 + lr;
      int rB0 = kv0 + 32 + lr, rB1 = kv0 + 48 + lr;
      int cA0 = kv0 + 4 * g, cA1 = kv0 + 16 + 4 * g;
      int cB0 = kv0 + 32 + 4 * g, cB1 = kv0 + 48 + 4 * g;
      if (c == 6) {                         // compile-time tail clamps
        rA0 = rA0 < NTOK ? rA0 : NTOK - 1; rA1 = NTOK - 1;
        rB0 = NTOK - 1; rB1 = NTOK - 1;
        cA0 = cA0 < 388 ? cA0 : 388; cA1 = 388; cB0 = 388; cB1 = 388;
      }
      Frag kA0, kA1, kB0, kB1, vA0, vA1, vB0, vB1;
      { const short* p;
        p = K_l + rA0 * KST + 4 * g; kA0.h.lo = *(const s16x4*)p; kA0.h.hi = *(const s16x4*)(p + 16);
        p = K_l + rA1 * KST + 4 * g; kA1.h.lo = *(const s16x4*)p; kA1.h.hi = *(const s16x4*)(p + 16);
        p = K_l + rB0 * KST + 4 * g; kB0.h.lo = *(const s16x4*)p; kB0.h.hi = *(const s16x4*)(p + 16);
        p = K_l + rB1 * KST + 4 * g; kB1.h.lo = *(const s16x4*)p; kB1.h.hi = *(const s16x4*)(p + 16);
        const short* v0r = Vt + lr * VST;
        const short* v1r = Vt + (16 + lr) * VST;
        vA0.h.lo = *(const s16x4*)(v0r + cA0); vA0.h.hi = *(const s16x4*)(v0r + cA1);
        vB0.h.lo = *(const s16x4*)(v0r + cB0); vB0.h.hi = *(const s16x4*)(v0r + cB1);
        vA1.h.lo = *(const s16x4*)(v1r + cA0); vA1.h.hi = *(const s16x4*)(v1r + cA1);
        vB1.h.lo = *(const s16x4*)(v1r + cB0); vB1.h.hi = *(const s16x4*)(v1r + cB1); }
      // C-init = mask + bias from 1-chunk-old regs (off critical path)
      f32x4 aL, aH;
      bb2f(bA[sl], aL, aH);
      f32x4 cc0 = mA0[sl] + aL, cc1 = mA1[sl] + aH, cc2, cc3;
      if (c < 6) {
        f32x4 bL, bH;
        bb2f(bB[sl], bL, bH);
        cc2 = mB0[sl] + bL; cc3 = mB1[sl] + bH;
      } else {
        const f32x4 neg = {-3e30f, -3e30f, -3e30f, -3e30f};
        cc2 = neg; cc3 = neg;
      }
      __builtin_amdgcn_s_setprio(1);        // T5: favor this wave thru compute
      f32x4 s0 = __builtin_amdgcn_mfma_f32_16x16x32_bf16(kA0.v, qf.v, cc0, 0,0,0);
      f32x4 s1 = __builtin_amdgcn_mfma_f32_16x16x32_bf16(kA1.v, qf.v, cc1, 0,0,0);
      f32x4 s2 = __builtin_amdgcn_mfma_f32_16x16x32_bf16(kB0.v, qf.v, cc2, 0,0,0);
      f32x4 s3 = __builtin_amdgcn_mfma_f32_16x16x32_bf16(kB1.v, qf.v, cc3, 0,0,0);
      // ONE merged softmax step for 64 kv
      float cmA = fmaxf(fmaxf(fmaxf(s0.x, s0.y), fmaxf(s0.z, s0.w)),
                        fmaxf(fmaxf(s1.x, s1.y), fmaxf(s1.z, s1.w)));
      float cmB = fmaxf(fmaxf(fmaxf(s2.x, s2.y), fmaxf(s2.z, s2.w)),
                        fmaxf(fmaxf(s3.x, s3.y), fmaxf(s3.z, s3.w)));
      float cm = fmaxf(cmA, cmB);
      if (__any(cm > mrun + 8.f)) {
        float tmx = fmaxf(cm, __shfl_xor(cm, 16));
        tmx = fmaxf(tmx, __shfl_xor(tmx, 32));
        const float mnew = fmaxf(mrun, tmx);
        const float al = fexp2((mrun - mnew) * L2E);
        #pragma unroll
        for (int rr = 0; rr < 4; ++rr) { o0[rr] *= al; o1[rr] *= al; }
        lrun *= al; mrun = mnew; nmrl = -mnew * L2E;
      }
      float p0  = fexp2(fmaf(s0.x, L2E, nmrl));
      float p1  = fexp2(fmaf(s0.y, L2E, nmrl));
      float p2  = fexp2(fmaf(s0.z, L2E, nmrl));
      float p3  = fexp2(fmaf(s0.w, L2E, nmrl));
      float p4  = fexp2(fmaf(s1.x, L2E, nmrl));
      float p5  = fexp2(fmaf(s1.y, L2E, nmrl));
      float p6  = fexp2(fmaf(s1.z, L2E, nmrl));
      float p7  = fexp2(fmaf(s1.w, L2E, nmrl));
      float p8  = fexp2(fmaf(s2.x, L2E, nmrl));
      float p9  = fexp2(fmaf(s2.y, L2E, nmrl));
      float p10 = fexp2(fmaf(s2.z, L2E, nmrl));
      float p11 = fexp2(fmaf(s2.w, L2E, nmrl));
      float p12 = fexp2(fmaf(s3.x, L2E, nmrl));
      float p13 = fexp2(fmaf(s3.y, L2E, nmrl));
      float p14 = fexp2(fmaf(s3.z, L2E, nmrl));
      float p15 = fexp2(fmaf(s3.w, L2E, nmrl));
      lrun += (((p0 + p1) + (p2 + p3)) + ((p4 + p5) + (p6 + p7)))
            + (((p8 + p9) + (p10 + p11)) + ((p12 + p13) + (p14 + p15)));
      PF pfA, pfB;
      asm("v_cvt_pk_bf16_f32 %0, %1, %2" : "=v"(pfA.u[0]) : "v"(p0),  "v"(p1));
      asm("v_cvt_pk_bf16_f32 %0, %1, %2" : "=v"(pfA.u[1]) : "v"(p2),  "v"(p3));
      asm("v_cvt_pk_bf16_f32 %0, %1, %2" : "=v"(pfA.u[2]) : "v"(p4),  "v"(p5));
      asm("v_cvt_pk_bf16_f32 %0, %1, %2" : "=v"(pfA.u[3]) : "v"(p6),  "v"(p7));
      asm("v_cvt_pk_bf16_f32 %0, %1, %2" : "=v"(pfB.u[0]) : "v"(p8),  "v"(p9));
      asm("v_cvt_pk_bf16_f32 %0, %1, %2" : "=v"(pfB.u[1]) : "v"(p10), "v"(p11));
      asm("v_cvt_pk_bf16_f32 %0, %1, %2" : "=v"(pfB.u[2]) : "v"(p12), "v"(p13));
      asm("v_cvt_pk_bf16_f32 %0, %1, %2" : "=v"(pfB.u[3]) : "v"(p14), "v"(p15));
      o0 = __builtin_amdgcn_mfma_f32_16x16x32_bf16(vA0.v, pfA.v, o0, 0, 0, 0);
      o1 = __builtin_amdgcn_mfma_f32_16x16x32_bf16(vA1.v, pfA.v, o1, 0, 0, 0);
      o0 = __builtin_amdgcn_mfma_f32_16x16x32_bf16(vB0.v, pfB.v, o0, 0, 0, 0);
      o1 = __builtin_amdgcn_mfma_f32_16x16x32_bf16(vB1.v, pfB.v, o1, 0, 0, 0);
      __builtin_amdgcn_s_setprio(0);
    }
    float lt = lrun + __shfl_xor(lrun, 16);
    lt += __shfl_xor(lt, 32);
    if (qrow < NTOK) {
      const float inv = 1.0f / lt;
      short* yb = y_ws + ((size_t)b * NTOK + qrow) * DIM + h * HD;
      s16x4 r0v, r1v;
      #pragma unroll
      for (int rr = 0; rr < 4; ++rr) { r0v[rr] = f2bf(o0[rr] * inv); r1v[rr] = f2bf(o1[rr] * inv); }
      *(s16x4*)(yb + 4 * g) = r0v;
      *(s16x4*)(yb + 16 + 4 * g) = r1v;
    }
  }
}

// ---------------- K3: out = y @ proj_w^T + proj_b -----------------------------
__global__ __launch_bounds__(256, 3)
void k_proj(const short* __restrict__ y_ws, const short* __restrict__ wp_bf,
            const float* __restrict__ pb, float* __restrict__ out) {
  __shared__ short ys[64 * 136];
  __shared__ short wl[128 * 136];
  const int t = threadIdx.x;
  const int m0 = blockIdx.x * 64;
  {
    const int r = t >> 2, c0 = (t & 3) * 32;
    const s16x4* src = (const s16x4*)(y_ws + (size_t)(m0 + r) * DIM + c0);
    short* dst = ys + r * 136 + c0;
    #pragma unroll
    for (int i = 0; i < 8; ++i) *(s16x4*)(dst + 4*i) = src[i];
  }
  {
    const int r = t >> 1, c0 = (t & 1) * 64;
    const short* src = wp_bf + (size_t)r * DIM + c0;
    short* dst = wl + r * 136 + c0;
    #pragma unroll
    for (int i = 0; i < 8; ++i)
      *(s16x8*)(dst + 8*i) = *(const s16x8*)(src + 8*i);
  }
  __syncthreads();
  const int l = t & 63, w = t >> 6, lr = l & 15, g = l >> 4;
  const int m = m0 + w * 16 + lr;
  f32x4 acc[8] = {};
  #pragma unroll
  for (int ks = 0; ks < 4; ++ks) {
    const int k0 = ks * 32 + 4 * g;
    Frag ya;
    const short* bp = ys + (w * 16 + lr) * 136 + k0;
    ya.h.lo = *(const s16x4*)bp; ya.h.hi = *(const s16x4*)(bp + 16);
    #pragma unroll
    for (int ct = 0; ct < 8; ++ct) {
      const short* ap = wl + (ct * 16 + lr) * 136 + k0;
      Frag wa; wa.h.lo = *(const s16x4*)ap; wa.h.hi = *(const s16x4*)(ap + 16);
      acc[ct] = __builtin_amdgcn_mfma_f32_16x16x32_bf16(wa.v, ya.v, acc[ct], 0, 0, 0);
    }
  }
  #pragma unroll
  for (int ct = 0; ct < 8; ++ct) {
    const int c0 = ct * 16 + 4 * g;
    const f32x4 pbv = *(const f32x4*)(pb + c0);
    f32x4 res = acc[ct] + pbv;
    *(f32x4*)(out + (size_t)m * DIM + c0) = res;
  }
}

extern "C" void kernel_launch(void* const* d_in, const int* in_sizes, int n_in,
                              void* d_out, int out_size, void* d_ws, size_t ws_size,
                              hipStream_t stream) {
  const float* x    = (const float*)d_in[0];
  const float* mask = (const float*)d_in[1];
  const float* bt   = (const float*)d_in[2];
  const int*   ri   = (const int*)d_in[3];
  const float* qkvw = (const float*)d_in[4];
  const float* pw   = (const float*)d_in[5];
  const float* pb   = (const float*)d_in[6];
  float* out = (float*)d_out;
  // ws layout: 4 x 25.69MB bf16 tensors + 1.3MB bias_perm + 128KB bf16 weights
  const size_t TEN = (size_t)256 * NH * NTOK * HD;   // 12,845,056
  short* q_ws = (short*)d_ws;
  short* k_ws = q_ws + TEN;
  short* v_ws = k_ws + TEN;
  short* y_ws = v_ws + TEN;
  short* bias_perm = y_ws + TEN;                     // NH*NTOK*BPQ shorts
  short* wq_bf = bias_perm + (size_t)NH * NTOK * BPQ; // 3*128*128 shorts
  short* wp_bf = wq_bf + 3 * DIM * DIM;               // 128*128 shorts
  k_prep<<<(NH * NTOK * BPQ + 255) / 256, 256, 0, stream>>>(bt, ri, bias_perm,
                                                            qkvw, pw, wq_bf, wp_bf);
  k_qkv<<<1568, 256, 0, stream>>>(x, wq_bf, q_ws, k_ws, v_ws);
  k_attn<<<1024, 640, 0, stream>>>(q_ws, k_ws, v_ws, mask, bias_perm, y_ws);
  k_proj<<<1568, 256, 0, stream>>>(y_ws, wp_bf, pb, out);
}

// Round 22
// 188.477 us; speedup vs baseline: 1.1941x; 1.0156x over previous
//
#include <hip/hip_runtime.h>
#include <hip/hip_bf16.h>
#include <stdint.h>

#define NTOK 392
#define DIM  128
#define NH   4
#define HD   32
#define KST  36    // K_lds stride (shorts): 18 dwords, measured conflict-free
#define VST  396   // Vt stride (shorts): 198 dwords (=6 mod 32, same family)
#define L2E  1.44269504f
#define BPQ  416   // bias_perm shorts per q-row (13*32)

typedef __attribute__((ext_vector_type(4))) float f32x4;
typedef __attribute__((ext_vector_type(4))) short s16x4;
typedef __attribute__((ext_vector_type(8))) short s16x8;

union Frag { s16x8 v; struct { s16x4 lo, hi; } h; };
union PF { s16x8 v; uint32_t u[4]; };

__device__ __forceinline__ short f2bf(float f) {
  union { float f; uint32_t u; } v; v.f = f;
  uint32_t r = v.u + 0x7fffu + ((v.u >> 16) & 1u);
  return (short)(r >> 16);
}
// RNE pack via HW (bit-identical to f2bf); 2 insts per 4 values
__device__ __forceinline__ s16x4 cvt4(f32x4 a) {
  union { s16x4 s; uint32_t u[2]; } r;
  asm("v_cvt_pk_bf16_f32 %0, %1, %2" : "=v"(r.u[0]) : "v"(a.x), "v"(a.y));
  asm("v_cvt_pk_bf16_f32 %0, %1, %2" : "=v"(r.u[1]) : "v"(a.z), "v"(a.w));
  return r.s;
}
// raw v_exp_f32 (args bounded: <= ~12 by defer-max; denorm flush OK)
__device__ __forceinline__ float fexp2(float x) {
  float r; asm("v_exp_f32 %0, %1" : "=v"(r) : "v"(x)); return r;
}
// bf16x8 -> 2x f32x4 (2 VALU per dword: shl16 / and-hi)
__device__ __forceinline__ void bb2f(s16x8 b, f32x4& lo, f32x4& hi) {
  union { s16x8 s; uint32_t u[4]; } x; x.s = b;
  union { uint32_t u; float f; } t;
  t.u = x.u[0] << 16;          lo.x = t.f;
  t.u = x.u[0] & 0xffff0000u;  lo.y = t.f;
  t.u = x.u[1] << 16;          lo.z = t.f;
  t.u = x.u[1] & 0xffff0000u;  lo.w = t.f;
  t.u = x.u[2] << 16;          hi.x = t.f;
  t.u = x.u[2] & 0xffff0000u;  hi.y = t.f;
  t.u = x.u[3] << 16;          hi.z = t.f;
  t.u = x.u[3] & 0xffff0000u;  hi.w = t.f;
}

// ---- K0: fused prep — bias -> frag-ordered bf16 (pad poisoned) + weights
// ---- -> bf16 (one-time) ----------------------------------------------------
__global__ void k_prep(const float* __restrict__ bt, const int* __restrict__ ri,
                       short* __restrict__ bias_perm,
                       const float* __restrict__ qkvw, const float* __restrict__ pw,
                       short* __restrict__ wq_bf, short* __restrict__ wp_bf) {
  int i = blockIdx.x * 256 + threadIdx.x;
  if (i < 3 * DIM * DIM) wq_bf[i] = f2bf(qkvw[i]);
  if (i < DIM * DIM)     wp_bf[i] = f2bf(pw[i]);
  if (i >= NH * NTOK * BPQ) return;
  int h = i / (NTOK * BPQ);
  int r = i - h * (NTOK * BPQ);
  int q = r / BPQ;
  int p = r - q * BPQ;               // c*32 + g*8 + hb*4 + j
  int c = p >> 5, w2 = p & 31;
  int g = w2 >> 3, hb = (w2 >> 2) & 1, jj = w2 & 3;
  int kv = c * 32 + hb * 16 + g * 4 + jj;
  float v = -3e30f;
  if (kv < NTOK) v = bt[ri[q * NTOK + kv] * NH + h];
  bias_perm[i] = f2bf(v);
}

// ------- K1: qkv = x @ qkv_w^T, bf16 out, q pre-scaled; fused z-loop ---------
__global__ __launch_bounds__(256, 3)
void k_qkv(const float* __restrict__ x, const short* __restrict__ wq_bf,
           short* __restrict__ q_ws, short* __restrict__ k_ws,
           short* __restrict__ v_ws) {
  __shared__ short xs[64 * 136];
  __shared__ short wl[128 * 136];
  const int t  = threadIdx.x;
  const int m0 = blockIdx.x * 64;
  {
    const int r = t >> 2, c0 = (t & 3) * 32;
    const float* src = x + (size_t)(m0 + r) * DIM + c0;
    short* dst = xs + r * 136 + c0;
    #pragma unroll
    for (int i = 0; i < 8; ++i)
      *(s16x4*)(dst + 4*i) = cvt4(*(const f32x4*)(src + 4*i));
  }
  const int l = t & 63, w = t >> 6, lr = l & 15, g = l >> 4;
  const int m = m0 + w * 16 + lr;
  const int b = m / NTOK;
  const int n = m - b * NTOK;
  #pragma unroll 1
  for (int z = 0; z < 3; ++z) {
    {
      const int r = t >> 1, c0 = (t & 1) * 64;
      const short* src = wq_bf + (size_t)(z * DIM + r) * DIM + c0;
      short* dst = wl + r * 136 + c0;
      #pragma unroll
      for (int i = 0; i < 8; ++i)
        *(s16x8*)(dst + 8*i) = *(const s16x8*)(src + 8*i);
    }
    __syncthreads();
    f32x4 acc[8] = {};
    #pragma unroll
    for (int ks = 0; ks < 4; ++ks) {
      const int k0 = ks * 32 + 4 * g;
      Frag xb;
      const short* bp = xs + (w * 16 + lr) * 136 + k0;
      xb.h.lo = *(const s16x4*)bp; xb.h.hi = *(const s16x4*)(bp + 16);
      #pragma unroll
      for (int ct = 0; ct < 8; ++ct) {
        const short* ap = wl + (ct * 16 + lr) * 136 + k0;
        Frag wa; wa.h.lo = *(const s16x4*)ap; wa.h.hi = *(const s16x4*)(ap + 16);
        acc[ct] = __builtin_amdgcn_mfma_f32_16x16x32_bf16(wa.v, xb.v, acc[ct], 0, 0, 0);
      }
    }
    short* outp = (z == 0) ? q_ws : (z == 1 ? k_ws : v_ws);
    const float scale = (z == 0) ? 0.17677669529663689f : 1.0f;
    #pragma unroll
    for (int ct = 0; ct < 8; ++ct) {
      const int c0 = ct * 16 + 4 * g;       // 4 consecutive channels
      const int hh = c0 >> 5, d = c0 & 31;
      f32x4 sc = acc[ct];
      sc.x *= scale; sc.y *= scale; sc.z *= scale; sc.w *= scale;
      *(s16x4*)(outp + (((size_t)b * NH + hh) * NTOK + n) * HD + d) = cvt4(sc);
    }
    __syncthreads();
  }
}

// ---- K2: per-(window,head) attention. KVBLK=64, 7 chunks/tile. -------------
// ---- r18/r19-verified body (135.5us, VGPR 88). launch_bounds (512,2) ->
// ---- VGPR cap 128 (hipcc 2nd arg == CUDA minBlocks/CU; (512,4) caps at 64).
// ---- setprio(1) around MFMA+softmax compute (T5, isolated win r18). --------
__global__ __launch_bounds__(512, 2)
void k_attn(const short* __restrict__ q_ws, const short* __restrict__ k_ws,
            const short* __restrict__ v_ws, const float* __restrict__ mask,
            const short* __restrict__ bias_perm, short* __restrict__ y_ws) {
  __shared__ short K_l[NTOK * KST];   // [392][36] shorts = 28224 B
  __shared__ short Vt[HD * VST];      // [32][396] shorts = 25344 B
  const int t = threadIdx.x;
  // XCD swizzle: 4 heads of one window land on the same XCD, adjacent slots
  const int j = blockIdx.x, xcd = j & 7, slot = j >> 3;
  const int b = (xcd << 5) | (slot >> 2);
  const int h = slot & 3;
  const size_t bh = (size_t)b * NH + h;
  const short* kp = k_ws + bh * NTOK * HD;
  const short* vp = v_ws + bh * NTOK * HD;
  const short* qp = q_ws + bh * NTOK * HD;
  const float* mp = mask + (size_t)b * NTOK * NTOK;
  const short* bph = bias_perm + (size_t)h * NTOK * BPQ;
  // stage K (real rows only; tail reads are clamped)
  for (int r = t; r < NTOK; r += 512) {
    short* dst = K_l + r * KST;
    const s16x4* src = (const s16x4*)(kp + r * HD);
    #pragma unroll
    for (int i = 0; i < 8; ++i) *(s16x4*)(dst + 4*i) = src[i];
  }
  // stage V transposed (real cols only; tail reads are clamped)
  for (int n = t; n < NTOK; n += 512) {
    union { s16x4 v4[8]; short s[32]; } vv;
    const s16x4* src = (const s16x4*)(vp + n * HD);
    #pragma unroll
    for (int i = 0; i < 8; ++i) vv.v4[i] = src[i];
    #pragma unroll
    for (int d = 0; d < 32; ++d) Vt[d * VST + n] = vv.s[d];
  }
  __syncthreads();
  const int l = t & 63, w = t >> 6, lr = l & 15, g = l >> 4;
  const int og0 = 4 * g, og1 = 16 + 4 * g;
  #pragma unroll 1
  for (int q0 = w * 16; q0 < NTOK; q0 += 128) {
    const int qrow = q0 + lr;
    const int qc = qrow < NTOK ? qrow : NTOK - 1;
    Frag qf;
    { const short* qa = qp + qc * HD + 4 * g;
      qf.h.lo = *(const s16x4*)qa; qf.h.hi = *(const s16x4*)(qa + 16); }
    const float* mrow = mp + (size_t)qc * NTOK;
    const short* brow = bph + qc * BPQ;
    // 2 fat slots (64 kv each), distance-1 prefetch, raw at issue
    f32x4 mA0[2], mA1[2], mB0[2], mB1[2];
    s16x8 bA[2], bB[2];
    mA0[0] = *(const f32x4*)(mrow + og0);
    mA1[0] = *(const f32x4*)(mrow + og1);
    mB0[0] = *(const f32x4*)(mrow + 32 + og0);
    mB1[0] = *(const f32x4*)(mrow + 32 + og1);
    bA[0]  = *(const s16x8*)(brow + g * 8);
    bB[0]  = *(const s16x8*)(brow + 32 + g * 8);
    f32x4 o0 = {0,0,0,0}, o1 = {0,0,0,0};
    float mrun = 0.f, nmrl = 0.f, lrun = 0.f;
    #pragma unroll
    for (int c = 0; c < 7; ++c) {
      const int sl = c & 1, nx = sl ^ 1;   // static after unroll
      if (c < 6) {                          // distance-1 prefetch of c+1
        const int base = (c + 1) * 64;
        if (c + 1 < 6) {
          mA0[nx] = *(const f32x4*)(mrow + base + og0);
          mA1[nx] = *(const f32x4*)(mrow + base + og1);
          mB0[nx] = *(const f32x4*)(mrow + base + 32 + og0);
          mB1[nx] = *(const f32x4*)(mrow + base + 32 + og1);
          bA[nx]  = *(const s16x8*)(brow + base + g * 8);
          bB[nx]  = *(const s16x8*)(brow + base + 32 + g * 8);
        } else {                            // tail: half A only (old chunk 12)
          int a0 = 384 + og0; if (a0 > 388) a0 = 388;
          mA0[nx] = *(const f32x4*)(mrow + a0);
          mA1[nx] = *(const f32x4*)(mrow + 388);
          bA[nx]  = *(const s16x8*)(brow + 384 + g * 8);
        }
      }
      const int kv0 = c * 64;
      int rA0 = kv0 + lr, rA1 = kv0 + 16 + lr;
      int rB0 = kv0 + 32 + lr, rB1 = kv0 + 48 + lr;
      int cA0 = kv0 + 4 * g, cA1 = kv0 + 16 + 4 * g;
      int cB0 = kv0 + 32 + 4 * g, cB1 = kv0 + 48 + 4 * g;
      if (c == 6) {                         // compile-time tail clamps
        rA0 = rA0 < NTOK ? rA0 : NTOK - 1; rA1 = NTOK - 1;
        rB0 = NTOK - 1; rB1 = NTOK - 1;
        cA0 = cA0 < 388 ? cA0 : 388; cA1 = 388; cB0 = 388; cB1 = 388;
      }
      Frag kA0, kA1, kB0, kB1, vA0, vA1, vB0, vB1;
      { const short* p;
        p = K_l + rA0 * KST + 4 * g; kA0.h.lo = *(const s16x4*)p; kA0.h.hi = *(const s16x4*)(p + 16);
        p = K_l + rA1 * KST + 4 * g; kA1.h.lo = *(const s16x4*)p; kA1.h.hi = *(const s16x4*)(p + 16);
        p = K_l + rB0 * KST + 4 * g; kB0.h.lo = *(const s16x4*)p; kB0.h.hi = *(const s16x4*)(p + 16);
        p = K_l + rB1 * KST + 4 * g; kB1.h.lo = *(const s16x4*)p; kB1.h.hi = *(const s16x4*)(p + 16);
        const short* v0r = Vt + lr * VST;
        const short* v1r = Vt + (16 + lr) * VST;
        vA0.h.lo = *(const s16x4*)(v0r + cA0); vA0.h.hi = *(const s16x4*)(v0r + cA1);
        vB0.h.lo = *(const s16x4*)(v0r + cB0); vB0.h.hi = *(const s16x4*)(v0r + cB1);
        vA1.h.lo = *(const s16x4*)(v1r + cA0); vA1.h.hi = *(const s16x4*)(v1r + cA1);
        vB1.h.lo = *(const s16x4*)(v1r + cB0); vB1.h.hi = *(const s16x4*)(v1r + cB1); }
      // C-init = mask + bias from 1-chunk-old regs (off critical path)
      f32x4 aL, aH;
      bb2f(bA[sl], aL, aH);
      f32x4 cc0 = mA0[sl] + aL, cc1 = mA1[sl] + aH, cc2, cc3;
      if (c < 6) {
        f32x4 bL, bH;
        bb2f(bB[sl], bL, bH);
        cc2 = mB0[sl] + bL; cc3 = mB1[sl] + bH;
      } else {
        const f32x4 neg = {-3e30f, -3e30f, -3e30f, -3e30f};
        cc2 = neg; cc3 = neg;
      }
      __builtin_amdgcn_s_setprio(1);        // T5: favor this wave thru compute
      f32x4 s0 = __builtin_amdgcn_mfma_f32_16x16x32_bf16(kA0.v, qf.v, cc0, 0,0,0);
      f32x4 s1 = __builtin_amdgcn_mfma_f32_16x16x32_bf16(kA1.v, qf.v, cc1, 0,0,0);
      f32x4 s2 = __builtin_amdgcn_mfma_f32_16x16x32_bf16(kB0.v, qf.v, cc2, 0,0,0);
      f32x4 s3 = __builtin_amdgcn_mfma_f32_16x16x32_bf16(kB1.v, qf.v, cc3, 0,0,0);
      // ONE merged softmax step for 64 kv
      float cmA = fmaxf(fmaxf(fmaxf(s0.x, s0.y), fmaxf(s0.z, s0.w)),
                        fmaxf(fmaxf(s1.x, s1.y), fmaxf(s1.z, s1.w)));
      float cmB = fmaxf(fmaxf(fmaxf(s2.x, s2.y), fmaxf(s2.z, s2.w)),
                        fmaxf(fmaxf(s3.x, s3.y), fmaxf(s3.z, s3.w)));
      float cm = fmaxf(cmA, cmB);
      if (__any(cm > mrun + 8.f)) {
        float tmx = fmaxf(cm, __shfl_xor(cm, 16));
        tmx = fmaxf(tmx, __shfl_xor(tmx, 32));
        const float mnew = fmaxf(mrun, tmx);
        const float al = fexp2((mrun - mnew) * L2E);
        #pragma unroll
        for (int rr = 0; rr < 4; ++rr) { o0[rr] *= al; o1[rr] *= al; }
        lrun *= al; mrun = mnew; nmrl = -mnew * L2E;
      }
      float p0  = fexp2(fmaf(s0.x, L2E, nmrl));
      float p1  = fexp2(fmaf(s0.y, L2E, nmrl));
      float p2  = fexp2(fmaf(s0.z, L2E, nmrl));
      float p3  = fexp2(fmaf(s0.w, L2E, nmrl));
      float p4  = fexp2(fmaf(s1.x, L2E, nmrl));
      float p5  = fexp2(fmaf(s1.y, L2E, nmrl));
      float p6  = fexp2(fmaf(s1.z, L2E, nmrl));
      float p7  = fexp2(fmaf(s1.w, L2E, nmrl));
      float p8  = fexp2(fmaf(s2.x, L2E, nmrl));
      float p9  = fexp2(fmaf(s2.y, L2E, nmrl));
      float p10 = fexp2(fmaf(s2.z, L2E, nmrl));
      float p11 = fexp2(fmaf(s2.w, L2E, nmrl));
      float p12 = fexp2(fmaf(s3.x, L2E, nmrl));
      float p13 = fexp2(fmaf(s3.y, L2E, nmrl));
      float p14 = fexp2(fmaf(s3.z, L2E, nmrl));
      float p15 = fexp2(fmaf(s3.w, L2E, nmrl));
      lrun += (((p0 + p1) + (p2 + p3)) + ((p4 + p5) + (p6 + p7)))
            + (((p8 + p9) + (p10 + p11)) + ((p12 + p13) + (p14 + p15)));
      PF pfA, pfB;
      asm("v_cvt_pk_bf16_f32 %0, %1, %2" : "=v"(pfA.u[0]) : "v"(p0),  "v"(p1));
      asm("v_cvt_pk_bf16_f32 %0, %1, %2" : "=v"(pfA.u[1]) : "v"(p2),  "v"(p3));
      asm("v_cvt_pk_bf16_f32 %0, %1, %2" : "=v"(pfA.u[2]) : "v"(p4),  "v"(p5));
      asm("v_cvt_pk_bf16_f32 %0, %1, %2" : "=v"(pfA.u[3]) : "v"(p6),  "v"(p7));
      asm("v_cvt_pk_bf16_f32 %0, %1, %2" : "=v"(pfB.u[0]) : "v"(p8),  "v"(p9));
      asm("v_cvt_pk_bf16_f32 %0, %1, %2" : "=v"(pfB.u[1]) : "v"(p10), "v"(p11));
      asm("v_cvt_pk_bf16_f32 %0, %1, %2" : "=v"(pfB.u[2]) : "v"(p12), "v"(p13));
      asm("v_cvt_pk_bf16_f32 %0, %1, %2" : "=v"(pfB.u[3]) : "v"(p14), "v"(p15));
      o0 = __builtin_amdgcn_mfma_f32_16x16x32_bf16(vA0.v, pfA.v, o0, 0, 0, 0);
      o1 = __builtin_amdgcn_mfma_f32_16x16x32_bf16(vA1.v, pfA.v, o1, 0, 0, 0);
      o0 = __builtin_amdgcn_mfma_f32_16x16x32_bf16(vB0.v, pfB.v, o0, 0, 0, 0);
      o1 = __builtin_amdgcn_mfma_f32_16x16x32_bf16(vB1.v, pfB.v, o1, 0, 0, 0);
      __builtin_amdgcn_s_setprio(0);
    }
    float lt = lrun + __shfl_xor(lrun, 16);
    lt += __shfl_xor(lt, 32);
    if (qrow < NTOK) {
      const float inv = 1.0f / lt;
      short* yb = y_ws + ((size_t)b * NTOK + qrow) * DIM + h * HD;
      s16x4 r0v, r1v;
      #pragma unroll
      for (int rr = 0; rr < 4; ++rr) { r0v[rr] = f2bf(o0[rr] * inv); r1v[rr] = f2bf(o1[rr] * inv); }
      *(s16x4*)(yb + 4 * g) = r0v;
      *(s16x4*)(yb + 16 + 4 * g) = r1v;
    }
  }
}

// ---------------- K3: out = y @ proj_w^T + proj_b -----------------------------
__global__ __launch_bounds__(256, 3)
void k_proj(const short* __restrict__ y_ws, const short* __restrict__ wp_bf,
            const float* __restrict__ pb, float* __restrict__ out) {
  __shared__ short ys[64 * 136];
  __shared__ short wl[128 * 136];
  const int t = threadIdx.x;
  const int m0 = blockIdx.x * 64;
  {
    const int r = t >> 2, c0 = (t & 3) * 32;
    const s16x4* src = (const s16x4*)(y_ws + (size_t)(m0 + r) * DIM + c0);
    short* dst = ys + r * 136 + c0;
    #pragma unroll
    for (int i = 0; i < 8; ++i) *(s16x4*)(dst + 4*i) = src[i];
  }
  {
    const int r = t >> 1, c0 = (t & 1) * 64;
    const short* src = wp_bf + (size_t)r * DIM + c0;
    short* dst = wl + r * 136 + c0;
    #pragma unroll
    for (int i = 0; i < 8; ++i)
      *(s16x8*)(dst + 8*i) = *(const s16x8*)(src + 8*i);
  }
  __syncthreads();
  const int l = t & 63, w = t >> 6, lr = l & 15, g = l >> 4;
  const int m = m0 + w * 16 + lr;
  f32x4 acc[8] = {};
  #pragma unroll
  for (int ks = 0; ks < 4; ++ks) {
    const int k0 = ks * 32 + 4 * g;
    Frag ya;
    const short* bp = ys + (w * 16 + lr) * 136 + k0;
    ya.h.lo = *(const s16x4*)bp; ya.h.hi = *(const s16x4*)(bp + 16);
    #pragma unroll
    for (int ct = 0; ct < 8; ++ct) {
      const short* ap = wl + (ct * 16 + lr) * 136 + k0;
      Frag wa; wa.h.lo = *(const s16x4*)ap; wa.h.hi = *(const s16x4*)(ap + 16);
      acc[ct] = __builtin_amdgcn_mfma_f32_16x16x32_bf16(wa.v, ya.v, acc[ct], 0, 0, 0);
    }
  }
  #pragma unroll
  for (int ct = 0; ct < 8; ++ct) {
    const int c0 = ct * 16 + 4 * g;
    const f32x4 pbv = *(const f32x4*)(pb + c0);
    f32x4 res = acc[ct] + pbv;
    *(f32x4*)(out + (size_t)m * DIM + c0) = res;
  }
}

extern "C" void kernel_launch(void* const* d_in, const int* in_sizes, int n_in,
                              void* d_out, int out_size, void* d_ws, size_t ws_size,
                              hipStream_t stream) {
  const float* x    = (const float*)d_in[0];
  const float* mask = (const float*)d_in[1];
  const float* bt   = (const float*)d_in[2];
  const int*   ri   = (const int*)d_in[3];
  const float* qkvw = (const float*)d_in[4];
  const float* pw   = (const float*)d_in[5];
  const float* pb   = (const float*)d_in[6];
  float* out = (float*)d_out;
  // ws layout: 4 x 25.69MB bf16 tensors + 1.3MB bias_perm + 128KB bf16 weights
  const size_t TEN = (size_t)256 * NH * NTOK * HD;   // 12,845,056
  short* q_ws = (short*)d_ws;
  short* k_ws = q_ws + TEN;
  short* v_ws = k_ws + TEN;
  short* y_ws = v_ws + TEN;
  short* bias_perm = y_ws + TEN;                     // NH*NTOK*BPQ shorts
  short* wq_bf = bias_perm + (size_t)NH * NTOK * BPQ; // 3*128*128 shorts
  short* wp_bf = wq_bf + 3 * DIM * DIM;               // 128*128 shorts
  k_prep<<<(NH * NTOK * BPQ + 255) / 256, 256, 0, stream>>>(bt, ri, bias_perm,
                                                            qkvw, pw, wq_bf, wp_bf);
  k_qkv<<<1568, 256, 0, stream>>>(x, wq_bf, q_ws, k_ws, v_ws);
  k_attn<<<1024, 512, 0, stream>>>(q_ws, k_ws, v_ws, mask, bias_perm, y_ws);
  k_proj<<<1568, 256, 0, stream>>>(y_ws, wp_bf, pb, out);
}